// Round 1
// baseline (304.004 us; speedup 1.0000x reference)
//
#include <hip/hip_runtime.h>

// Beam-search select step.
// Inputs (setup_inputs order):
//   d_in[0] input_ids   (BATCH*NB, 512) int32   -- UNUSED by reference
//   d_in[1] next_scores (BATCH, 16)     float32
//   d_in[2] next_tokens (BATCH, 16)     int32
//   d_in[3] next_indices(BATCH, 16)     int32
//   d_in[4] done        (BATCH,)        bool (1 byte)
//   d_in[5] pad_token_id (1,) int32
//   d_in[6] eos_token_id (1,) int32
//   d_in[7] num_beams    (1,) int32  (== 8, compile-time constant here)
// Output: d_out = [beam_scores | beam_tokens | beam_src], each BATCH*8,
//         read back as one flat float32 array -> write tokens/src as floats.

#define BATCH 16384
#define NB 8
#define TWO_NB 16

__global__ __launch_bounds__(256) void beam_select_kernel(
    const float* __restrict__ next_scores,
    const int*   __restrict__ next_tokens,
    const int*   __restrict__ next_indices,
    const unsigned char* __restrict__ done,
    const int*   __restrict__ pad_p,
    const int*   __restrict__ eos_p,
    float*       __restrict__ out)
{
    const int row = blockIdx.x * blockDim.x + threadIdx.x;
    if (row >= BATCH) return;

    const int eos = *eos_p;
    const int pad = *pad_p;
    const int base = row * TWO_NB;

    // Load the 16 candidate tokens with two int4 vector loads each 16B.
    const int4* t4 = reinterpret_cast<const int4*>(next_tokens + base);
    const int4 ta = t4[0], tb = t4[1], tc = t4[2], td = t4[3];
    const int t[16] = { ta.x, ta.y, ta.z, ta.w,  tb.x, tb.y, tb.z, tb.w,
                        tc.x, tc.y, tc.z, tc.w,  td.x, td.y, td.z, td.w };

    // Non-eos mask (bit j set if token j != eos).
    unsigned ne = 0u;
    #pragma unroll
    for (int j = 0; j < 16; ++j)
        ne |= (t[j] != eos ? 1u : 0u) << j;

    // Stable argsort by is_eos ascending == positions of set bits of:
    //   low 16 bits: non-eos columns, high 16 bits: eos columns.
    unsigned m = ne | ((~ne & 0xFFFFu) << 16);

    const bool d = (done[row] != 0);

    float os[NB], ot[NB], osr[NB];
    #pragma unroll
    for (int k = 0; k < NB; ++k) {
        const int p = __ffs(m) - 1;   // k-th selected position (bit index)
        m &= (m - 1u);                // clear lowest set bit
        const int j = p & 15;         // column within the row
        // Gather via global reloads (L1-hot); avoids runtime-indexed
        // register arrays that would spill to scratch.
        os[k]  = d ? 0.0f        : next_scores[base + j];
        ot[k]  = d ? (float)pad  : (float)next_tokens[base + j];
        osr[k] = d ? 0.0f        : (float)(next_indices[base + j] + row * NB);
    }

    float4* o0 = reinterpret_cast<float4*>(out + (size_t)row * NB);
    float4* o1 = reinterpret_cast<float4*>(out + (size_t)BATCH * NB + (size_t)row * NB);
    float4* o2 = reinterpret_cast<float4*>(out + (size_t)2 * BATCH * NB + (size_t)row * NB);
    o0[0] = make_float4(os[0], os[1], os[2], os[3]);
    o0[1] = make_float4(os[4], os[5], os[6], os[7]);
    o1[0] = make_float4(ot[0], ot[1], ot[2], ot[3]);
    o1[1] = make_float4(ot[4], ot[5], ot[6], ot[7]);
    o2[0] = make_float4(osr[0], osr[1], osr[2], osr[3]);
    o2[1] = make_float4(osr[4], osr[5], osr[6], osr[7]);
}

extern "C" void kernel_launch(void* const* d_in, const int* in_sizes, int n_in,
                              void* d_out, int out_size, void* d_ws, size_t ws_size,
                              hipStream_t stream) {
    (void)in_sizes; (void)n_in; (void)out_size; (void)d_ws; (void)ws_size;

    const float* next_scores        = (const float*)d_in[1];
    const int*   next_tokens        = (const int*)  d_in[2];
    const int*   next_indices       = (const int*)  d_in[3];
    const unsigned char* done       = (const unsigned char*)d_in[4];
    const int*   pad_p              = (const int*)  d_in[5];
    const int*   eos_p              = (const int*)  d_in[6];
    float*       out                = (float*)d_out;

    const int block = 256;
    const int grid  = (BATCH + block - 1) / block;
    beam_select_kernel<<<grid, block, 0, stream>>>(
        next_scores, next_tokens, next_indices, done, pad_p, eos_p, out);
}